// Round 1
// baseline (3442.694 us; speedup 1.0000x reference)
//
#include <hip/hip_runtime.h>
#include <math.h>

// Transformer-XL relative attention, fp32 reference-precision version.
// B=4 N=16 L=1024 D=64. Outputs: out [B,N,L,D] then weight [B,N,L,L], concat flat.
//
// rel_shift(pos)[i,j] == pos[i, j - i + (L-1)] for j<=i (upper triangle masked).

#define Bq 4
#define Nh 16
#define Lq 1024
#define Dh 64
#define TQ 8      // query rows per block
#define NT 256    // threads per block

__device__ __forceinline__ float wave_max(float v) {
    #pragma unroll
    for (int o = 32; o > 0; o >>= 1) v = fmaxf(v, __shfl_xor(v, o));
    return v;
}
__device__ __forceinline__ float wave_sum(float v) {
    #pragma unroll
    for (int o = 32; o > 0; o >>= 1) v += __shfl_xor(v, o);
    return v;
}

__global__ __launch_bounds__(NT) void relattn_kernel(
    const float* __restrict__ qc, const float* __restrict__ qp,
    const float* __restrict__ K, const float* __restrict__ V,
    const float* __restrict__ P, float* __restrict__ out,
    float* __restrict__ wout)
{
    __shared__ __align__(16) float s_scores[TQ][Lq];  // 32 KB
    __shared__ __align__(16) float s_qc[TQ][Dh];      // 2 KB
    __shared__ __align__(16) float s_qp[TQ][Dh];      // 2 KB
    __shared__ __align__(16) float s_out[4][TQ][Dh];  // 8 KB

    const int tid  = threadIdx.x;
    const int bn   = blockIdx.x / (Lq / TQ);   // 0..63  (b*16+n)
    const int qt   = blockIdx.x % (Lq / TQ);   // 0..127
    const int n    = bn % Nh;
    const int i0   = qt * TQ;

    const float* qc_b = qc + ((size_t)bn * Lq + i0) * Dh;
    const float* qp_b = qp + ((size_t)bn * Lq + i0) * Dh;
    const float* K_b  = K  + (size_t)bn * Lq * Dh;
    const float* V_b  = V  + (size_t)bn * Lq * Dh;
    const float* P_n  = P  + (size_t)n  * Lq * Dh;

    // ---- Phase 1: stage query tiles into LDS ----
    if (tid < 128) {
        int r = tid >> 4, c = tid & 15;
        ((float4*)s_qc[r])[c] = ((const float4*)(qc_b + r * Dh))[c];
    } else {
        int t = tid - 128;
        int r = t >> 4, c = t & 15;
        ((float4*)s_qp[r])[c] = ((const float4*)(qp_b + r * Dh))[c];
    }
    __syncthreads();

    // ---- Phase 2a: content scores  s[r][j] = QC[i0+r] . K[j] ----
    for (int j = tid; j < Lq; j += NT) {
        const float4* krow = (const float4*)(K_b + (size_t)j * Dh);
        float acc[TQ];
        #pragma unroll
        for (int r = 0; r < TQ; r++) acc[r] = 0.f;
        #pragma unroll
        for (int c = 0; c < 16; c++) {
            float4 kv = krow[c];
            #pragma unroll
            for (int r = 0; r < TQ; r++) {
                float4 q = ((const float4*)s_qc[r])[c];
                acc[r] += q.x * kv.x + q.y * kv.y + q.z * kv.z + q.w * kv.w;
            }
        }
        #pragma unroll
        for (int r = 0; r < TQ; r++) s_scores[r][j] = acc[r];
    }
    __syncthreads();

    // ---- Phase 2b: positional scores, scatter by rel_shift ----
    // s[r][j] += QP[i] . P[p]  with  j = p + i - (L-1), i = i0+r ; only j>=0.
    for (int p = tid; p < Lq; p += NT) {
        const float4* prow = (const float4*)(P_n + (size_t)p * Dh);
        float acc[TQ];
        #pragma unroll
        for (int r = 0; r < TQ; r++) acc[r] = 0.f;
        #pragma unroll
        for (int c = 0; c < 16; c++) {
            float4 pv = prow[c];
            #pragma unroll
            for (int r = 0; r < TQ; r++) {
                float4 q = ((const float4*)s_qp[r])[c];
                acc[r] += q.x * pv.x + q.y * pv.y + q.z * pv.z + q.w * pv.w;
            }
        }
        #pragma unroll
        for (int r = 0; r < TQ; r++) {
            int i = i0 + r;
            int j = p + i - (Lq - 1);
            if (j >= 0) s_scores[r][j] += acc[r];
        }
    }
    __syncthreads();

    // ---- Phase 3: per-row softmax (wave w owns rows 2w, 2w+1), write weight ----
    {
        const int wid = tid >> 6, lane = tid & 63;
        #pragma unroll
        for (int rr = 0; rr < 2; rr++) {
            int r = wid * 2 + rr;
            int i = i0 + r;
            float mx = -INFINITY;
            for (int j = lane; j <= i; j += 64) mx = fmaxf(mx, s_scores[r][j]);
            mx = wave_max(mx);
            float sum = 0.f;
            for (int j = lane; j < Lq; j += 64) {
                float w = 0.f;
                if (j <= i) { w = __expf((s_scores[r][j] - mx) * 0.125f); sum += w; }
                s_scores[r][j] = w;
            }
            sum = wave_sum(sum);
            float inv = 1.0f / sum;
            float* wrow = wout + ((size_t)bn * Lq + i) * Lq;
            for (int j = lane; j < Lq; j += 64) {
                float w = s_scores[r][j] * inv;
                s_scores[r][j] = w;
                wrow[j] = w;
            }
        }
    }
    __syncthreads();

    // ---- Phase 4: out[r][d] = sum_j w[r][j] * V[j][d] ----
    {
        const int d = tid & 63, ch = tid >> 6;
        float acc[TQ];
        #pragma unroll
        for (int r = 0; r < TQ; r++) acc[r] = 0.f;
        const int jend  = i0 + TQ;                 // rows only attend j <= i0+TQ-1
        const int jbeg  = ch * (Lq / 4);
        const int jstop = (jbeg + Lq / 4 < jend) ? (jbeg + Lq / 4) : jend;
        for (int j = jbeg; j < jstop; j++) {
            float v = V_b[(size_t)j * Dh + d];
            #pragma unroll
            for (int r = 0; r < TQ; r++) acc[r] += s_scores[r][j] * v;
        }
        #pragma unroll
        for (int r = 0; r < TQ; r++) s_out[ch][r][d] = acc[r];
    }
    __syncthreads();

    for (int e = tid; e < TQ * Dh; e += NT) {
        int r = e / Dh, dd = e % Dh;
        float o = s_out[0][r][dd] + s_out[1][r][dd] + s_out[2][r][dd] + s_out[3][r][dd];
        out[((size_t)bn * Lq + (i0 + r)) * Dh + dd] = o;
    }
}

extern "C" void kernel_launch(void* const* d_in, const int* in_sizes, int n_in,
                              void* d_out, int out_size, void* d_ws, size_t ws_size,
                              hipStream_t stream) {
    const float* qc = (const float*)d_in[0];
    const float* qp = (const float*)d_in[1];
    const float* K  = (const float*)d_in[2];
    const float* V  = (const float*)d_in[3];
    const float* P  = (const float*)d_in[4];
    // d_in[5] = mask: fixed causal triu(k=1) — hardcoded in the kernel.

    float* out  = (float*)d_out;
    float* wout = out + (size_t)Bq * Nh * Lq * Dh;   // weight follows out

    dim3 grid(Bq * Nh * (Lq / TQ));   // 64 * 128 = 8192 blocks
    relattn_kernel<<<grid, NT, 0, stream>>>(qc, qp, K, V, P, out, wout);
}

// Round 2
// 499.586 us; speedup vs baseline: 6.8911x; 6.8911x over previous
//
#include <hip/hip_runtime.h>
#include <math.h>

// Transformer-XL relative attention, bf16-MFMA version.
// B=4 N=16 L=1024 D=64. Outputs: out [B,N,L,D] fp32, then weight [B,N,L,L] fp32.
// rel_shift(pos)[i,j] == pos[i, j - i + (L-1)], only j<=i survives the causal mask.

#define Bq 4
#define Nh 16
#define Lq 1024
#define Dh 64
#define TQ 16     // query rows per block
#define NT 256
#define LPAD 1028 // 1024 + 4 -> LDS row stride ≡ 4 mod 32: 2-way banks (free)

typedef __attribute__((ext_vector_type(8))) short bf16x8;
typedef __attribute__((ext_vector_type(4))) float f32x4;

__device__ __forceinline__ unsigned short f2bf(float f) {
    union { float f; unsigned int u; } v; v.f = f;
    unsigned int u = v.u;
    unsigned int r = u + 0x7FFFu + ((u >> 16) & 1u);  // RNE
    return (unsigned short)(r >> 16);
}

__device__ __forceinline__ bf16x8 ldg8(const unsigned short* p) {
    return *(const bf16x8*)p;
}

__device__ __forceinline__ float wave_max(float v) {
    #pragma unroll
    for (int o = 32; o > 0; o >>= 1) v = fmaxf(v, __shfl_xor(v, o));
    return v;
}
__device__ __forceinline__ float wave_sum(float v) {
    #pragma unroll
    for (int o = 32; o > 0; o >>= 1) v += __shfl_xor(v, o);
    return v;
}

// ---------- prep: fp32 -> bf16 convert ----------
__global__ __launch_bounds__(256) void cvt_bf16_kernel(
    const float* __restrict__ src, unsigned short* __restrict__ dst, int n4)
{
    int idx = blockIdx.x * 256 + threadIdx.x;
    if (idx >= n4) return;
    float4 v = ((const float4*)src)[idx];
    ushort4 o;
    o.x = f2bf(v.x); o.y = f2bf(v.y); o.z = f2bf(v.z); o.w = f2bf(v.w);
    ((ushort4*)dst)[idx] = o;
}

// ---------- prep: V [bn][j][d] fp32 -> Vt [bn][d][j] bf16 ----------
__global__ __launch_bounds__(256) void vt_kernel(
    const float* __restrict__ V, unsigned short* __restrict__ Vt)
{
    __shared__ float t[64][65];
    int bn = blockIdx.x >> 4, jt = blockIdx.x & 15;
    int tid = threadIdx.x;
    int d = tid & 63, q = tid >> 6;
    const float* vb = V + ((size_t)(bn * Lq + jt * 64)) * Dh;
    #pragma unroll
    for (int r = 0; r < 16; r++) {
        int jl = r * 4 + q;
        t[jl][d] = vb[(size_t)jl * Dh + d];
    }
    __syncthreads();
    int dd = tid >> 2, jb = (tid & 3) << 4;
    bf16x8 s0, s1;
    #pragma unroll
    for (int jj = 0; jj < 8; jj++) {
        s0[jj] = (short)f2bf(t[jb + jj][dd]);
        s1[jj] = (short)f2bf(t[jb + 8 + jj][dd]);
    }
    unsigned short* drow = Vt + (((size_t)(bn * 64 + dd)) << 10) + (jt << 6) + jb;
    *(bf16x8*)drow = s0;
    *(bf16x8*)(drow + 8) = s1;
}

// ---------- main ----------
__global__ __launch_bounds__(NT, 2) void relattn_kernel(
    const unsigned short* __restrict__ QCb, const unsigned short* __restrict__ QPb,
    const unsigned short* __restrict__ Kb,  const unsigned short* __restrict__ Pb,
    const unsigned short* __restrict__ Vtb,
    float* __restrict__ out, float* __restrict__ wout)
{
    __shared__ float s_s[TQ][LPAD];   // 65792 B

    const int tid  = threadIdx.x;
    const int w    = tid >> 6, lane = tid & 63;
    const int ln   = lane & 15, quad = lane >> 4;
    const int bn   = blockIdx.x >> 6, qt = blockIdx.x & 63;
    const int nh   = bn & 15;
    const int i0   = qt << 4, i1 = i0 + 15;

    // A fragments: A[m=ln][k=quad*8+j], contiguous 8 bf16 per lane
    const unsigned short* qcrow = QCb + (((size_t)(bn << 10) + i0 + ln) << 6) + (quad << 3);
    const unsigned short* qprow = QPb + (((size_t)(bn << 10) + i0 + ln) << 6) + (quad << 3);
    bf16x8 aC0 = ldg8(qcrow), aC1 = ldg8(qcrow + 32);
    bf16x8 aP0 = ldg8(qprow), aP1 = ldg8(qprow + 32);

    // ---- Phase A: content scores S = QC . K^T (causal tiles only) ----
    const unsigned short* kbase = Kb + (((size_t)(bn << 10)) << 6) + (quad << 3);
    #pragma unroll
    for (int ct = 0; ct < 16; ct++) {
        int c0 = ((ct << 2) + w) << 4;           // interleave tiles across waves
        if (c0 <= i1) {
            const unsigned short* kr = kbase + ((size_t)(c0 + ln) << 6);
            f32x4 acc = {0.f, 0.f, 0.f, 0.f};
            acc = __builtin_amdgcn_mfma_f32_16x16x32_bf16(aC0, ldg8(kr),      acc, 0, 0, 0);
            acc = __builtin_amdgcn_mfma_f32_16x16x32_bf16(aC1, ldg8(kr + 32), acc, 0, 0, 0);
            #pragma unroll
            for (int rg = 0; rg < 4; rg++)        // C: col=ln, row=quad*4+rg
                s_s[(quad << 2) + rg][c0 + ln] = acc[rg];
        }
    }
    __syncthreads();

    // ---- Phase B: pos scores T = QP . P^T, scatter-add with rel_shift ----
    const unsigned short* pbase = Pb + (((size_t)(nh << 10)) << 6) + (quad << 3);
    #pragma unroll
    for (int ct = 0; ct < 16; ct++) {
        int p0 = ((ct << 2) + w) << 4;
        if (p0 + i0 + 30 >= 1023) {              // some j = p+i-1023 >= 0 in tile
            const unsigned short* pr = pbase + ((size_t)(p0 + ln) << 6);
            f32x4 acc = {0.f, 0.f, 0.f, 0.f};
            acc = __builtin_amdgcn_mfma_f32_16x16x32_bf16(aP0, ldg8(pr),      acc, 0, 0, 0);
            acc = __builtin_amdgcn_mfma_f32_16x16x32_bf16(aP1, ldg8(pr + 32), acc, 0, 0, 0);
            int p = p0 + ln;
            #pragma unroll
            for (int rg = 0; rg < 4; rg++) {
                int row = (quad << 2) + rg;
                int j = p + i0 + row - 1023;     // j <= i always (p <= 1023)
                if (j >= 0) s_s[row][j] += acc[rg];   // unique (row,j) per lane: no race
            }
        }
    }
    __syncthreads();

    // ---- Phase C: per-row softmax (wave w owns rows 4w..4w+3), write W fp32 ----
    #pragma unroll
    for (int rr = 0; rr < 4; rr++) {
        int r = (w << 2) + rr;
        int i = i0 + r;
        float mx = -3.0e38f;
        #pragma unroll
        for (int c = 0; c < 4; c++) {
            int j = (c << 8) + (lane << 2);
            float4 v = *(float4*)&s_s[r][j];
            if (j     <= i) mx = fmaxf(mx, v.x);
            if (j + 1 <= i) mx = fmaxf(mx, v.y);
            if (j + 2 <= i) mx = fmaxf(mx, v.z);
            if (j + 3 <= i) mx = fmaxf(mx, v.w);
        }
        mx = wave_max(mx);
        float sum = 0.f;
        #pragma unroll
        for (int c = 0; c < 4; c++) {
            int j = (c << 8) + (lane << 2);
            float4 v = *(float4*)&s_s[r][j];
            float4 e;
            e.x = (j     <= i) ? __expf((v.x - mx) * 0.125f) : 0.f;
            e.y = (j + 1 <= i) ? __expf((v.y - mx) * 0.125f) : 0.f;
            e.z = (j + 2 <= i) ? __expf((v.z - mx) * 0.125f) : 0.f;
            e.w = (j + 3 <= i) ? __expf((v.w - mx) * 0.125f) : 0.f;
            sum += e.x + e.y + e.z + e.w;
            *(float4*)&s_s[r][j] = e;
        }
        sum = wave_sum(sum);
        float inv = 1.0f / sum;
        float* wrow = wout + (((size_t)(bn << 10) + i) << 10);
        #pragma unroll
        for (int c = 0; c < 4; c++) {
            int j = (c << 8) + (lane << 2);
            float4 e = *(float4*)&s_s[r][j];
            e.x *= inv; e.y *= inv; e.z *= inv; e.w *= inv;
            *(float4*)&s_s[r][j] = e;             // weights for PV
            *(float4*)&wrow[j]   = e;             // W output (zeros where masked)
        }
    }
    __syncthreads();

    // ---- Phase D: out = W . V via MFMA, A from LDS (f32->bf16), B from Vt ----
    f32x4 o = {0.f, 0.f, 0.f, 0.f};
    const int n0 = w << 4;
    const unsigned short* vtb = Vtb + (((size_t)(bn << 6) + n0 + ln) << 10);
    const int ksteps = (i0 + 16 + 31) >> 5;       // j <= i1 only; rest of W is 0
    for (int ks = 0; ks < ksteps; ks++) {
        int k0 = (ks << 5) + (quad << 3);
        float4 a0 = *(float4*)&s_s[ln][k0];
        float4 a1 = *(float4*)&s_s[ln][k0 + 4];
        bf16x8 af;
        af[0] = (short)f2bf(a0.x); af[1] = (short)f2bf(a0.y);
        af[2] = (short)f2bf(a0.z); af[3] = (short)f2bf(a0.w);
        af[4] = (short)f2bf(a1.x); af[5] = (short)f2bf(a1.y);
        af[6] = (short)f2bf(a1.z); af[7] = (short)f2bf(a1.w);
        bf16x8 vb = ldg8(vtb + k0);
        o = __builtin_amdgcn_mfma_f32_16x16x32_bf16(af, vb, o, 0, 0, 0);
    }
    float* obase = out + (((size_t)(bn << 10) + i0) << 6);
    #pragma unroll
    for (int rg = 0; rg < 4; rg++)
        obase[((size_t)((quad << 2) + rg) << 6) + n0 + ln] = o[rg];
}

extern "C" void kernel_launch(void* const* d_in, const int* in_sizes, int n_in,
                              void* d_out, int out_size, void* d_ws, size_t ws_size,
                              hipStream_t stream) {
    const float* qc = (const float*)d_in[0];
    const float* qp = (const float*)d_in[1];
    const float* K  = (const float*)d_in[2];
    const float* V  = (const float*)d_in[3];
    const float* P  = (const float*)d_in[4];
    // d_in[5]: causal mask, hardcoded.

    float* out  = (float*)d_out;
    float* wout = out + (size_t)Bq * Nh * Lq * Dh;

    const size_t NQ = (size_t)Bq * Nh * Lq * Dh;   // 4,194,304
    const size_t NP = (size_t)Nh * Lq * Dh;        // 1,048,576
    unsigned short* QCb = (unsigned short*)d_ws;
    unsigned short* QPb = QCb + NQ;
    unsigned short* Kb  = QPb + NQ;
    unsigned short* Pb  = Kb  + NQ;
    unsigned short* Vtb = Pb  + NP;                // total 34 MB of ws

    cvt_bf16_kernel<<<(NQ / 4 + 255) / 256, 256, 0, stream>>>(qc, QCb, (int)(NQ / 4));
    cvt_bf16_kernel<<<(NQ / 4 + 255) / 256, 256, 0, stream>>>(qp, QPb, (int)(NQ / 4));
    cvt_bf16_kernel<<<(NQ / 4 + 255) / 256, 256, 0, stream>>>(K,  Kb,  (int)(NQ / 4));
    cvt_bf16_kernel<<<(NP / 4 + 255) / 256, 256, 0, stream>>>(P,  Pb,  (int)(NP / 4));
    vt_kernel<<<Bq * Nh * 16, 256, 0, stream>>>(V, Vtb);

    relattn_kernel<<<Bq * Nh * (Lq / TQ), NT, 0, stream>>>(QCb, QPb, Kb, Pb, Vtb, out, wout);
}

// Round 3
// 488.936 us; speedup vs baseline: 7.0412x; 1.0218x over previous
//
#include <hip/hip_runtime.h>
#include <math.h>

// Transformer-XL relative attention, bf16-MFMA, fused-softmax version.
// B=4 N=16 L=1024 D=64. Outputs: out [B,N,L,D] fp32, then weight [B,N,L,L] fp32.
// rel_shift(pos)[i,j] == pos[i, j - i + (L-1)], only j<=i survives the causal mask.

#define Bq 4
#define Nh 16
#define Lq 1024
#define Dh 64
#define TQ 16     // query rows per block
#define NT 256
#define LPAD 1028 // fp32 row stride in LDS (bytes: 4112); +4 pad -> 2-way banks (free)

typedef __attribute__((ext_vector_type(8))) short bf16x8;
typedef __attribute__((ext_vector_type(4))) float f32x4;

__device__ __forceinline__ unsigned short f2bf(float f) {
    union { float f; unsigned int u; } v; v.f = f;
    unsigned int u = v.u;
    unsigned int r = u + 0x7FFFu + ((u >> 16) & 1u);  // RNE
    return (unsigned short)(r >> 16);
}

__device__ __forceinline__ bf16x8 pack8(float4 a, float4 b) {
    bf16x8 o;
    o[0] = (short)f2bf(a.x); o[1] = (short)f2bf(a.y);
    o[2] = (short)f2bf(a.z); o[3] = (short)f2bf(a.w);
    o[4] = (short)f2bf(b.x); o[5] = (short)f2bf(b.y);
    o[6] = (short)f2bf(b.z); o[7] = (short)f2bf(b.w);
    return o;
}

__device__ __forceinline__ bf16x8 ldg8(const unsigned short* p) {
    return *(const bf16x8*)p;
}

__device__ __forceinline__ float wave_max(float v) {
    #pragma unroll
    for (int o = 32; o > 0; o >>= 1) v = fmaxf(v, __shfl_xor(v, o));
    return v;
}
__device__ __forceinline__ float wave_sum(float v) {
    #pragma unroll
    for (int o = 32; o > 0; o >>= 1) v += __shfl_xor(v, o);
    return v;
}

// ---------- prep: K and P fp32 -> bf16 (one kernel, two ranges) ----------
__global__ __launch_bounds__(256) void cvt_kp_kernel(
    const float* __restrict__ K, const float* __restrict__ P,
    unsigned short* __restrict__ Kb, unsigned short* __restrict__ Pb)
{
    int b = blockIdx.x;
    const float* src; unsigned short* dst; int idx;
    if (b < 4096) { idx = b * 256 + threadIdx.x; src = K; dst = Kb; }
    else          { idx = (b - 4096) * 256 + threadIdx.x; src = P; dst = Pb; }
    float4 v = ((const float4*)src)[idx];
    ushort4 o;
    o.x = f2bf(v.x); o.y = f2bf(v.y); o.z = f2bf(v.z); o.w = f2bf(v.w);
    ((ushort4*)dst)[idx] = o;
}

// ---------- prep: V [bn][j][d] fp32 -> Vt [bn][d][j] bf16 ----------
__global__ __launch_bounds__(256) void vt_kernel(
    const float* __restrict__ V, unsigned short* __restrict__ Vt)
{
    __shared__ float t[64][65];
    int bn = blockIdx.x >> 4, jt = blockIdx.x & 15;
    int tid = threadIdx.x;
    int d = tid & 63, q = tid >> 6;
    const float* vb = V + ((size_t)(bn * Lq + jt * 64)) * Dh;
    #pragma unroll
    for (int r = 0; r < 16; r++) {
        int jl = r * 4 + q;
        t[jl][d] = vb[(size_t)jl * Dh + d];
    }
    __syncthreads();
    int dd = tid >> 2, jb = (tid & 3) << 4;
    bf16x8 s0, s1;
    #pragma unroll
    for (int jj = 0; jj < 8; jj++) {
        s0[jj] = (short)f2bf(t[jb + jj][dd]);
        s1[jj] = (short)f2bf(t[jb + 8 + jj][dd]);
    }
    unsigned short* drow = Vt + (((size_t)(bn * 64 + dd)) << 10) + (jt << 6) + jb;
    *(bf16x8*)drow = s0;
    *(bf16x8*)(drow + 8) = s1;
}

// ---------- main ----------
__global__ __launch_bounds__(NT, 2) void relattn_kernel(
    const float* __restrict__ QC, const float* __restrict__ QP,
    const unsigned short* __restrict__ Kb, const unsigned short* __restrict__ Pb,
    const unsigned short* __restrict__ Vtb,
    float* __restrict__ out, float* __restrict__ wout)
{
    __shared__ __align__(16) float s_s[TQ][LPAD];   // 65792 B

    const int tid  = threadIdx.x;
    const int w    = tid >> 6, lane = tid & 63;
    const int ln   = lane & 15, quad = lane >> 4;
    const int bn   = blockIdx.x >> 6, qt = blockIdx.x & 63;
    const int nh   = bn & 15;
    const int i0   = qt << 4, i1 = i0 + 15;

    // A fragments from fp32 directly: A[m=ln][k=quad*8+j]
    const float* qcrow = QC + (((size_t)(bn << 10) + i0 + ln) << 6) + (quad << 3);
    const float* qprow = QP + (((size_t)(bn << 10) + i0 + ln) << 6) + (quad << 3);
    bf16x8 aC0 = pack8(*(const float4*)qcrow,        *(const float4*)(qcrow + 4));
    bf16x8 aC1 = pack8(*(const float4*)(qcrow + 32), *(const float4*)(qcrow + 36));
    bf16x8 aP0 = pack8(*(const float4*)qprow,        *(const float4*)(qprow + 4));
    bf16x8 aP1 = pack8(*(const float4*)(qprow + 32), *(const float4*)(qprow + 36));

    // ---- Phase A: content scores S = QC . K^T (causal tiles only) ----
    const unsigned short* kbase = Kb + (((size_t)(bn << 10)) << 6) + (quad << 3);
    #pragma unroll
    for (int ct = 0; ct < 16; ct++) {
        int c0 = ((ct << 2) + w) << 4;           // interleave tiles across waves
        if (c0 <= i1) {
            const unsigned short* kr = kbase + ((size_t)(c0 + ln) << 6);
            f32x4 acc = {0.f, 0.f, 0.f, 0.f};
            acc = __builtin_amdgcn_mfma_f32_16x16x32_bf16(aC0, ldg8(kr),      acc, 0, 0, 0);
            acc = __builtin_amdgcn_mfma_f32_16x16x32_bf16(aC1, ldg8(kr + 32), acc, 0, 0, 0);
            #pragma unroll
            for (int rg = 0; rg < 4; rg++)        // C: col=ln, row=quad*4+rg
                s_s[(quad << 2) + rg][c0 + ln] = acc[rg];
        }
    }
    __syncthreads();

    // ---- Phase B: pos scores T = QP . P^T, scatter-add with rel_shift ----
    const unsigned short* pbase = Pb + (((size_t)(nh << 10)) << 6) + (quad << 3);
    #pragma unroll
    for (int ct = 0; ct < 16; ct++) {
        int p0 = ((ct << 2) + w) << 4;
        if (p0 + i0 + 30 >= 1023) {              // some j = p+i-1023 >= 0 in tile
            const unsigned short* pr = pbase + ((size_t)(p0 + ln) << 6);
            f32x4 acc = {0.f, 0.f, 0.f, 0.f};
            acc = __builtin_amdgcn_mfma_f32_16x16x32_bf16(aP0, ldg8(pr),      acc, 0, 0, 0);
            acc = __builtin_amdgcn_mfma_f32_16x16x32_bf16(aP1, ldg8(pr + 32), acc, 0, 0, 0);
            int p = p0 + ln;
            #pragma unroll
            for (int rg = 0; rg < 4; rg++) {
                int row = (quad << 2) + rg;
                int j = p + i0 + row - 1023;     // j <= i always (p <= 1023)
                if (j >= 0) s_s[row][j] += acc[rg];   // unique (row,j) per lane: no race
            }
        }
    }
    __syncthreads();

    // ---- Phase C: in-register softmax; write W fp32; pack bf16 weights in-place ----
    // Wave w owns rows 4w..4w+3. Lane owns j = c*256 + lane*4 + e, c=0..3, e=0..3.
    #pragma unroll
    for (int rr = 0; rr < 4; rr++) {
        int r = (w << 2) + rr;
        int i = i0 + r;
        float v[16];
        #pragma unroll
        for (int c = 0; c < 4; c++) {
            float4 t = *(float4*)&s_s[r][(c << 8) + (lane << 2)];
            v[c * 4 + 0] = t.x; v[c * 4 + 1] = t.y;
            v[c * 4 + 2] = t.z; v[c * 4 + 3] = t.w;
        }
        float mx = -3.0e38f;
        #pragma unroll
        for (int c = 0; c < 4; c++) {
            int j = (c << 8) + (lane << 2);
            #pragma unroll
            for (int e = 0; e < 4; e++)
                if (j + e <= i) mx = fmaxf(mx, v[c * 4 + e]);
        }
        mx = wave_max(mx);
        float sum = 0.f;
        #pragma unroll
        for (int c = 0; c < 4; c++) {
            int j = (c << 8) + (lane << 2);
            #pragma unroll
            for (int e = 0; e < 4; e++) {
                float t = (j + e <= i) ? __expf((v[c * 4 + e] - mx) * 0.125f) : 0.f;
                sum += t;
                v[c * 4 + e] = t;
            }
        }
        sum = wave_sum(sum);
        float inv = 1.0f / sum;
        float* wrow = wout + (((size_t)(bn << 10) + i) << 10);
        char*  brow = (char*)s_s + (size_t)r * (LPAD * 4);   // bf16 row, in-place
        #pragma unroll
        for (int c = 0; c < 4; c++) {
            int j = (c << 8) + (lane << 2);
            float4 e;
            e.x = v[c * 4 + 0] * inv; e.y = v[c * 4 + 1] * inv;
            e.z = v[c * 4 + 2] * inv; e.w = v[c * 4 + 3] * inv;
            *(float4*)&wrow[j] = e;              // W output (coalesced, zeros in mask)
            ushort4 h;
            h.x = f2bf(e.x); h.y = f2bf(e.y); h.z = f2bf(e.z); h.w = f2bf(e.w);
            *(ushort4*)(brow + (size_t)j * 2) = h;   // bf16 A-operand for Phase D
        }
    }
    __syncthreads();

    // ---- Phase D: out = W . V via MFMA, A = packed bf16 rows, B = Vt global ----
    f32x4 o = {0.f, 0.f, 0.f, 0.f};
    const int n0 = w << 4;
    const unsigned short* vtb = Vtb + (((size_t)(bn << 6) + n0 + ln) << 10);
    const char* abase = (const char*)s_s + (size_t)ln * (LPAD * 4);
    const int ksteps = (i0 + 16 + 31) >> 5;       // j <= i1 only; rest of W is 0
    for (int ks = 0; ks < ksteps; ks++) {
        int k0 = (ks << 5) + (quad << 3);
        bf16x8 af = *(const bf16x8*)(abase + (size_t)k0 * 2);
        bf16x8 vb = ldg8(vtb + (ks << 5) + (quad << 3));
        o = __builtin_amdgcn_mfma_f32_16x16x32_bf16(af, vb, o, 0, 0, 0);
    }
    float* obase = out + (((size_t)(bn << 10) + i0) << 6);
    #pragma unroll
    for (int rg = 0; rg < 4; rg++)
        obase[((size_t)((quad << 2) + rg) << 6) + n0 + ln] = o[rg];
}

extern "C" void kernel_launch(void* const* d_in, const int* in_sizes, int n_in,
                              void* d_out, int out_size, void* d_ws, size_t ws_size,
                              hipStream_t stream) {
    const float* qc = (const float*)d_in[0];
    const float* qp = (const float*)d_in[1];
    const float* K  = (const float*)d_in[2];
    const float* V  = (const float*)d_in[3];
    const float* P  = (const float*)d_in[4];
    // d_in[5]: causal mask, hardcoded.

    float* out  = (float*)d_out;
    float* wout = out + (size_t)Bq * Nh * Lq * Dh;

    const size_t NQ = (size_t)Bq * Nh * Lq * Dh;   // 4,194,304
    const size_t NP = (size_t)Nh * Lq * Dh;        // 1,048,576
    unsigned short* Kb  = (unsigned short*)d_ws;
    unsigned short* Pb  = Kb + NQ;
    unsigned short* Vtb = Pb + NP;                 // total 18 MB of ws

    cvt_kp_kernel<<<4096 + 1024, 256, 0, stream>>>(K, P, Kb, Pb);
    vt_kernel<<<Bq * Nh * 16, 256, 0, stream>>>(V, Vtb);
    relattn_kernel<<<Bq * Nh * (Lq / TQ), NT, 0, stream>>>(qc, qp, Kb, Pb, Vtb, out, wout);
}